// Round 13
// baseline (151.060 us; speedup 1.0000x reference)
//
#include <hip/hip_runtime.h>

#define I_DIM 17
#define H_DIM 128
#define T_DIM 19
#define B_DIM 32768
#define M_ROWS 128
#define NTHR 512
#define GRID (B_DIM / M_ROWS) /* 256 = one block per CU, ONE pass */
#define XI 323                /* T*I */
#define NF (M_ROWS * XI)      /* 41344 floats per block */
#define XSLOT 4352            /* per-t x slot: 8 rowgrp x 512B (k0..15) + 256B k16 plane */

/* LDS: single H buffer per group (staggered pipeline makes dbuf unnecessary) */
#define GB0 0                 /* G0.H: rows 0..63   [row][col] 256B stride, swizzled */
#define GB1 16384             /* G1.H: rows 64..127 */
#define OFF_X 32768           /* 19 x 4352 = 82688 */
#define OFF_WO 115456         /* 8 frags x 1024 = 8192 */
#define LDS_TOT 123648

typedef __bf16 bf16x8 __attribute__((ext_vector_type(8)));
typedef float f32x4 __attribute__((ext_vector_type(4)));
typedef float f32x4u __attribute__((ext_vector_type(4), aligned(4)));
union FragU { bf16x8 v; unsigned short s[8]; uint4 u; };

#define K1 1.4426950408889634f
#define K2 2.8853900817779268f

__device__ __forceinline__ unsigned short f2bf(float f) {
    union { float f; unsigned u; } x; x.f = f;
    return (unsigned short)((x.u + 0x8000u) >> 16);
}

/* TRANSPOSED gates MFMA for one batch N-tile QT_ (16 rows) of one group.
   D: lane l15 = batch-row (within tile), reg r -> gate-col cg*16+4q+r. */
#define MFMA_Q(QT_, GB_, XB_, XK_, REC_) do {                                     \
    _Pragma("unroll") for (int g = 0; g < 4; ++g)                                 \
        acc[QT_][g] = bias[g];                                                    \
    FragU fx; fx.u = (uint4){0u, 0u, 0u, 0u};                                     \
    if (q < 2)                                                                    \
        fx.v = *(const bf16x8*)(smem + (XB_) + (QT_) * 512);                      \
    else if (q == 2)                                                              \
        fx.s[0] = *(const unsigned short*)(smem + (XK_) + (QT_) * 32);            \
    _Pragma("unroll") for (int g = 0; g < 4; ++g)                                 \
        acc[QT_][g] = __builtin_amdgcn_mfma_f32_16x16x32_bf16(wihr[g], fx.v, acc[QT_][g], 0, 0, 0); \
    if (REC_) {                                                                   \
        _Pragma("unroll") for (int kk = 0; kk < 4; ++kk) {                        \
            bf16x8 a = *(const bf16x8*)(smem + vkk[kk] + ((GB_) + (QT_) * 4096)); \
            _Pragma("unroll") for (int g = 0; g < 4; ++g)                         \
                acc[QT_][g] = __builtin_amdgcn_mfma_f32_16x16x32_bf16(whh[kk][g], a, acc[QT_][g], 0, 0, 0); \
        }                                                                         \
    }                                                                             \
} while (0)

/* elementwise + one packed b64 h-write for N-tile QT_ (consumes acc[QT_]) */
#define ELEM_Q(QT_, GB_, CST_) do {                                               \
    unsigned long long hp = 0ull;                                                 \
    _Pragma("unroll") for (int r = 0; r < 4; ++r) {                               \
        float ui = __builtin_amdgcn_exp2f(acc[QT_][0][r]);                        \
        float uf = __builtin_amdgcn_exp2f(acc[QT_][1][r]);                        \
        float vg = __builtin_amdgcn_exp2f(acc[QT_][2][r]);                        \
        float uo = __builtin_amdgcn_exp2f(acc[QT_][3][r]);                        \
        float A_ = 1.f + ui, F_ = 1.f + uf, G_ = 1.f + vg;                        \
        float AG = A_ * G_;                                                       \
        int ci = (QT_) * 4 + r;                                                   \
        float c = (CST_[ci] * AG + (1.f - vg) * F_) * __builtin_amdgcn_rcpf(F_ * AG); \
        CST_[ci] = c;                                                             \
        float vc = __builtin_amdgcn_exp2f(-K2 * c);                               \
        float h = (1.f - vc) * __builtin_amdgcn_rcpf((1.f + uo) * (1.f + vc));    \
        union { float f; unsigned u; } hu; hu.f = h;                              \
        hp |= (unsigned long long)((hu.u + 0x8000u) >> 16) << (16 * r);           \
    }                                                                             \
    *(unsigned long long*)(smem + vwrT + ((GB_) + (QT_) * 4096)) = hp;            \
} while (0)

/* y^T for one group: wave covers batch N-tile (w>>1), out-col tile (w&1) */
#define Y_T(GB_, YP_) do {                                                        \
    f32x4 ya = {0.f, 0.f, 0.f, 0.f};                                              \
    _Pragma("unroll") for (int kk = 0; kk < 4; ++kk) {                            \
        bf16x8 wa = *(const bf16x8*)(smem + vwo + kk * 1024);                     \
        bf16x8 hb = *(const bf16x8*)(smem + vkk[kk] + ((GB_) + 0) + yrt4);        \
        ya = __builtin_amdgcn_mfma_f32_16x16x32_bf16(wa, hb, ya, 0, 0, 0);        \
    }                                                                             \
    if (yct == 0) {                                                               \
        *(f32x4u*)(YP_) = ya + ybo;                                               \
    } else if (q == 0) {                                                          \
        (YP_)[0] = ya[0] + ybo[0];                                                \
    }                                                                             \
} while (0)

__global__ __launch_bounds__(NTHR)
__attribute__((amdgpu_waves_per_eu(2, 2)))
void flowlstm(
    const float* __restrict__ x, const float* __restrict__ W_ih,
    const float* __restrict__ W_hh, const float* __restrict__ b_ih,
    const float* __restrict__ b_hh, const float* __restrict__ W_out,
    const float* __restrict__ b_out, float* __restrict__ out)
{
    __shared__ __align__(16) unsigned char smem[LDS_TOT];
    const int tid = threadIdx.x;
    const int w = tid >> 6, lane = tid & 63, l15 = lane & 15, q = lane >> 4;
    const int cg = w;                      /* wave owns gate-cols g*128 + cg*16 + (4q+r) */
    const int b0 = blockIdx.x * M_ROWS;

    /* ---- bulk x stage: coalesced dwords -> bf16 frag slots (k<16) + k16 plane ---- */
    {
        const float* xb = x + (size_t)b0 * XI;
        for (int j = 0; j < 81; ++j) {
            int f = tid + j * NTHR;
            if (f < NF) {
                float v = xb[f];
                unsigned uf_ = (unsigned)f;
                unsigned row = (uf_ * 51943u) >> 24;      /* f / 323 */
                unsigned s = uf_ - row * 323u;
                unsigned t = (s * 61681u) >> 20;          /* s / 17 */
                unsigned k = s - t * 17u;
                unsigned a;
                if (k == 16) a = OFF_X + t * XSLOT + 4096 + row * 2;
                else a = OFF_X + t * XSLOT + (row >> 4) * 512 + (k >> 3) * 256
                       + (row & 15) * 16 + (k & 7) * 2;
                *(unsigned short*)(smem + a) = f2bf(v);
            }
        }
    }
    /* ---- W_out fragments -> LDS (8 frags = ct*4+kk, N pad 17->32) ---- */
    {
        int ln = tid & 63, f = tid >> 6;
        int kk = f & 3, ct = f >> 2;
        int o = ct * 16 + (ln & 15);
        int kb = kk * 32 + (ln >> 4) * 8;
        FragU fu;
        #pragma unroll
        for (int e = 0; e < 8; ++e)
            fu.s[e] = (o < I_DIM) ? f2bf(W_out[o * H_DIM + kb + e]) : (unsigned short)0;
        *(uint4*)(smem + OFF_WO + f * 1024 + ln * 16) = fu.u;
    }
    /* gate scale: i,f,o -> -K1 ; g -> -K2 */
    float gsc[4] = { -K1, -K1, -K2, -K1 };

    /* ---- W_hh fragments in registers, PRE-SCALED (A-operand; 64 regs) ---- */
    bf16x8 whh[4][4];
    #pragma unroll
    for (int kk = 0; kk < 4; ++kk)
        #pragma unroll
        for (int g = 0; g < 4; ++g) {
            int n = g * H_DIM + cg * 16 + l15;
            const float* s = W_hh + n * H_DIM + kk * 32 + q * 8;
            FragU fu;
            #pragma unroll
            for (int e = 0; e < 8; ++e) fu.s[e] = f2bf(s[e] * gsc[g]);
            whh[kk][g] = fu.v;
        }
    /* ---- W_ih fragments in registers, PRE-SCALED (A-operand, K pad 17->32) ---- */
    bf16x8 wihr[4];
    #pragma unroll
    for (int g = 0; g < 4; ++g) {
        int n = g * H_DIM + cg * 16 + l15;
        FragU fu;
        #pragma unroll
        for (int e = 0; e < 8; ++e) {
            int k = q * 8 + e;
            fu.s[e] = (k < I_DIM) ? f2bf(W_ih[n * I_DIM + k] * gsc[g]) : (unsigned short)0;
        }
        wihr[g] = fu.v;
    }
    /* bias per (g, reg r): col = g*128 + cg*16 + 4q + r */
    f32x4 bias[4];
    #pragma unroll
    for (int g = 0; g < 4; ++g)
        #pragma unroll
        for (int r = 0; r < 4; ++r) {
            int col = g * H_DIM + cg * 16 + 4 * q + r;
            bias[g][r] = (b_ih[col] + b_hh[col]) * gsc[g];
        }
    /* ---- t-invariant LDS vaddrs ---- */
    const unsigned xr7 = (unsigned)((l15 & 7) << 4);
    unsigned vkk[4];
    #pragma unroll
    for (int kk = 0; kk < 4; ++kk)
        vkk[kk] = (unsigned)(l15 * 256 + ((kk * 64 + q * 16) ^ xr7));
    const unsigned vwrT = (unsigned)(l15 * 256 + (((cg * 16 + 4 * q) * 2) ^ xr7));
    const int yct = w & 1;
    const unsigned yrt4 = (unsigned)((w >> 1) * 4096);
    const unsigned vwo = (unsigned)(OFF_WO + yct * 4096 + lane * 16);
    f32x4 ybo;
    #pragma unroll
    for (int r = 0; r < 4; ++r) {
        int col = yct * 16 + 4 * q + r;
        ybo[r] = b_out[col < I_DIM ? col : 16];
    }
    unsigned xyA  = (unsigned)(OFF_X + (q < 2 ? q * 256 : 0) + l15 * 16);
    unsigned xk16 = (unsigned)(OFF_X + 4096 + l15 * 2);
    float* ypG0 = out + (size_t)(b0 + (w >> 1) * 16 + l15) * XI + (yct ? 16 : 4 * q);
    float* ypG1 = ypG0 + (size_t)64 * XI;

    float cstA[16], cstB[16];
    #pragma unroll
    for (int i = 0; i < 16; ++i) { cstA[i] = 0.f; cstB[i] = 0.f; }

    f32x4 acc[4][4];   /* shared between groups: ELEM(prev, q) then MFMA(cur, q) */

    __syncthreads();   /* staging visible */

    /* ---- R0: MFMA G0(t0), no recurrence ---- */
    MFMA_Q(0, GB0, xyA, xk16, 0);
    MFMA_Q(1, GB0, xyA, xk16, 0);
    MFMA_Q(2, GB0, xyA, xk16, 0);
    MFMA_Q(3, GB0, xyA, xk16, 0);
    __syncthreads();
    /* ---- R1: ELEM G0(t0) || MFMA G1(t0) ---- */
    ELEM_Q(0, GB0, cstA); MFMA_Q(0, GB1, xyA + 2048, xk16 + 128, 0);
    ELEM_Q(1, GB0, cstA); MFMA_Q(1, GB1, xyA + 2048, xk16 + 128, 0);
    ELEM_Q(2, GB0, cstA); MFMA_Q(2, GB1, xyA + 2048, xk16 + 128, 0);
    ELEM_Q(3, GB0, cstA); MFMA_Q(3, GB1, xyA + 2048, xk16 + 128, 0);
    __syncthreads();
    xyA += XSLOT; xk16 += XSLOT;

    /* ---- k = 1..18: two staggered regions per step ---- */
    #pragma unroll 1
    for (int k = 1; k < T_DIM; ++k) {
        /* region A: ELEM G1(k-1) || MFMA G0(k); Y G0(k-1) */
        ELEM_Q(0, GB1, cstB); MFMA_Q(0, GB0, xyA, xk16, 1);
        ELEM_Q(1, GB1, cstB); MFMA_Q(1, GB0, xyA, xk16, 1);
        Y_T(GB0, ypG0);
        ELEM_Q(2, GB1, cstB); MFMA_Q(2, GB0, xyA, xk16, 1);
        ELEM_Q(3, GB1, cstB); MFMA_Q(3, GB0, xyA, xk16, 1);
        __syncthreads();
        /* region B: ELEM G0(k) || MFMA G1(k); Y G1(k-1) */
        ELEM_Q(0, GB0, cstA); MFMA_Q(0, GB1, xyA + 2048, xk16 + 128, 1);
        ELEM_Q(1, GB0, cstA); MFMA_Q(1, GB1, xyA + 2048, xk16 + 128, 1);
        Y_T(GB1, ypG1);
        ELEM_Q(2, GB0, cstA); MFMA_Q(2, GB1, xyA + 2048, xk16 + 128, 1);
        ELEM_Q(3, GB0, cstA); MFMA_Q(3, GB1, xyA + 2048, xk16 + 128, 1);
        __syncthreads();
        xyA += XSLOT; xk16 += XSLOT;
        ypG0 += I_DIM; ypG1 += I_DIM;
    }

    /* ---- tail: ELEM G1(18) + Y G0(18); then Y G1(18) ---- */
    ELEM_Q(0, GB1, cstB);
    ELEM_Q(1, GB1, cstB);
    Y_T(GB0, ypG0);
    ELEM_Q(2, GB1, cstB);
    ELEM_Q(3, GB1, cstB);
    __syncthreads();
    Y_T(GB1, ypG1);
}

extern "C" void kernel_launch(void* const* d_in, const int* in_sizes, int n_in,
                              void* d_out, int out_size, void* d_ws, size_t ws_size,
                              hipStream_t stream) {
    const float* x     = (const float*)d_in[0];
    const float* W_ih  = (const float*)d_in[1];
    const float* W_hh  = (const float*)d_in[2];
    const float* b_ih  = (const float*)d_in[3];
    const float* b_hh  = (const float*)d_in[4];
    const float* W_out = (const float*)d_in[5];
    const float* b_out = (const float*)d_in[6];
    float* out = (float*)d_out;

    dim3 grid(GRID), block(NTHR);
    flowlstm<<<grid, block, 0, stream>>>(x, W_ih, W_hh, b_ih, b_hh, W_out, b_out, out);
}